// Round 13
// baseline (124.545 us; speedup 1.0000x reference)
//
#include <hip/hip_runtime.h>
#include <hip/hip_bf16.h>
#include <stdint.h>

typedef unsigned short ushort_t;
typedef __bf16 bf16x8 __attribute__((ext_vector_type(8)));
typedef float f32x4 __attribute__((ext_vector_type(4)));

#define T_TOK 8192
#define H_DIM 1024
#define E_EXP 8
#define BM 128
#define BN 128
#define BK 64
#define NKT (H_DIM / BK)               // 16
#define NWG_G 2304                     // 2048 bulk slots + 256 tail slots

#define CNT_STRIDE 64
#define RTOK 32
#define RBLOCKS (T_TOK / RTOK)         // 256
#define TP_BLOCKS ((H_DIM / 32) * (H_DIM / 32) * E_EXP)  // 8192

static __device__ __forceinline__ ushort_t f2bf(float f) {
  union { float f; uint32_t u; } c; c.f = f;
  uint32_t u = c.u;
  uint32_t r = u + 0x7FFFu + ((u >> 16) & 1u);  // RNE
  return (ushort_t)(r >> 16);
}

// ---- Fused: router (blocks 0..255) + expert_w transpose (blocks 256..) -----
// Router also ZEROES its 32 token rows of out (f32) -- the GEMM epilogue
// accumulates directly into out via hardware f32 atomics (combine kernel
// eliminated; saves ~100 MB of y-indirection traffic + one launch).
__global__ __launch_bounds__(256) void router_transpose(
    const float* __restrict__ x, const float* __restrict__ gw,
    const float* __restrict__ gb, const float* __restrict__ ew,
    float* __restrict__ out_final,
    float* __restrict__ out_idx, float* __restrict__ out_probs,
    int* __restrict__ counts, int* __restrict__ tok, float* __restrict__ wts,
    ushort_t* __restrict__ x_bf, ushort_t* __restrict__ wT)
{
  __shared__ int   sm_eid[RTOK * 2];
  __shared__ float sm_wt[RTOK * 2];
  __shared__ int   lcnt[E_EXP], lbase[E_EXP], lpos[E_EXP];
  __shared__ float tile[32][33];

  const int tid = threadIdx.x;

  if (blockIdx.x >= RBLOCKS) {
    // ---------------- transpose: ew [E,K,N] f32 -> wT [E,N,K] bf16 ----------
    const int tb = blockIdx.x - RBLOCKS;
    const int e = tb >> 10;
    const int n0 = (tb & 31) * 32, k0 = ((tb >> 5) & 31) * 32;
    const float* we = ew + (size_t)e * H_DIM * H_DIM;
    ushort_t* wTe = wT + (size_t)e * H_DIM * H_DIM;
    const int tx = tid & 31, ty = tid >> 5;  // 32 x 8
#pragma unroll
    for (int i = 0; i < 4; i++)
      tile[ty + 8 * i][tx] = we[(size_t)(k0 + ty + 8 * i) * H_DIM + n0 + tx];
    __syncthreads();
#pragma unroll
    for (int i = 0; i < 4; i++)
      wTe[(size_t)(n0 + ty + 8 * i) * H_DIM + k0 + tx] = f2bf(tile[tx][ty + 8 * i]);
    return;
  }

  // ------------------------------- router -----------------------------------
  const int wave = tid >> 6, l = tid & 63;
  if (tid < E_EXP) { lcnt[tid] = 0; lpos[tid] = 0; }

  const int t0 = blockIdx.x * RTOK;

  // Zero this block's 32 rows of out (f32) for the GEMM's atomic accumulate.
  {
    float4 z4 = make_float4(0.f, 0.f, 0.f, 0.f);
    float4* oz = reinterpret_cast<float4*>(out_final + (size_t)t0 * H_DIM);
#pragma unroll
    for (int i = 0; i < (RTOK * H_DIM / 4) / 256; i++)
      oz[tid + i * 256] = z4;
  }
  __syncthreads();

  for (int it = 0; it < RTOK / 4; it++) {
    const int lt = wave * (RTOK / 4) + it;
    const int t = t0 + lt;
    const float* xt = x + (size_t)t * H_DIM;
    float acc[E_EXP];
#pragma unroll
    for (int e = 0; e < E_EXP; e++) acc[e] = 0.f;
#pragma unroll
    for (int i = 0; i < 4; i++) {
      const int h = (i * 64 + l) * 4;
      const float4 xv = *reinterpret_cast<const float4*>(xt + h);
      ushort4 b;
      b.x = f2bf(xv.x); b.y = f2bf(xv.y); b.z = f2bf(xv.z); b.w = f2bf(xv.w);
      *reinterpret_cast<ushort4*>(x_bf + (size_t)t * H_DIM + h) = b;
#pragma unroll
      for (int e = 0; e < E_EXP; e++) {
        const float4 g = *reinterpret_cast<const float4*>(gw + e * H_DIM + h);
        acc[e] += xv.x * g.x + xv.y * g.y + xv.z * g.z + xv.w * g.w;
      }
    }
#pragma unroll
    for (int e = 0; e < E_EXP; e++) {
      float v = acc[e];
#pragma unroll
      for (int off = 32; off; off >>= 1) v += __shfl_xor(v, off);
      acc[e] = v;
    }
    if (l == 0) {
      float lg[E_EXP], pb[E_EXP];
      float m = -1e30f;
#pragma unroll
      for (int e = 0; e < E_EXP; e++) { lg[e] = acc[e] + gb[e]; m = fmaxf(m, lg[e]); }
      float s = 0.f;
#pragma unroll
      for (int e = 0; e < E_EXP; e++) { pb[e] = expf(lg[e] - m); s += pb[e]; }
      const float inv = 1.f / s;
#pragma unroll
      for (int e = 0; e < E_EXP; e++) {
        pb[e] *= inv;
        out_probs[(size_t)t * E_EXP + e] = pb[e];
      }
      int i0 = 0; float p0 = pb[0];
#pragma unroll
      for (int e = 1; e < E_EXP; e++) if (pb[e] > p0) { p0 = pb[e]; i0 = e; }
      int i1 = -1; float p1 = -1.f;
#pragma unroll
      for (int e = 0; e < E_EXP; e++) if (e != i0 && pb[e] > p1) { p1 = pb[e]; i1 = e; }
      out_idx[(size_t)t * 2 + 0] = (float)i0;
      out_idx[(size_t)t * 2 + 1] = (float)i1;
      const float rn = 1.f / (p0 + p1);
      sm_eid[lt * 2 + 0] = i0; sm_wt[lt * 2 + 0] = p0 * rn;
      sm_eid[lt * 2 + 1] = i1; sm_wt[lt * 2 + 1] = p1 * rn;
    }
  }
  __syncthreads();

  if (tid < RTOK * 2) atomicAdd(&lcnt[sm_eid[tid]], 1);
  __syncthreads();
  if (tid < E_EXP) lbase[tid] = atomicAdd(&counts[tid * CNT_STRIDE], lcnt[tid]);
  __syncthreads();
  if (tid < RTOK * 2) {
    const int e = sm_eid[tid];
    const int p = lbase[e] + atomicAdd(&lpos[e], 1);
    const int dst = e * T_TOK + p;
    tok[dst] = t0 + (tid >> 1);        // plain token index
    wts[dst] = sm_wt[tid];
  }
}

// ------------------- Grouped GEMM -- m97/m103 structure ---------------------
// 128x128 tile, BK=64, 256 threads (2x2 waves), SINGLE-buffered 32 KiB LDS,
// plain 2-barrier loop, 3+ blocks/CU (cross-block overlap hides the barrier
// drain, m114; R11 measured 53.6 us, 0 conflicts, VGPR 60).
// Epilogue: hardware f32 atomicAdd of w*(acc+bias) directly into out[token]
// (out pre-zeroed by the router) -- no y buffer, no combine kernel.
//   bid 0..2047   : bulk 128x128 tile (slot bid>>3, 0..255) of expert bid&7.
//   bid 2048..2303: tail 64x128 tile of expert bid&7.
#define GLDS16(gp, lp)                                                         \
  __builtin_amdgcn_global_load_lds(                                            \
      (const __attribute__((address_space(1))) void*)(gp),                     \
      (__attribute__((address_space(3))) void*)(lp), 16, 0, 0)

__global__ __launch_bounds__(256, 3) void moe_gemm(
    const ushort_t* __restrict__ x_bf, const ushort_t* __restrict__ wT,
    const float* __restrict__ bias, int* __restrict__ counts,
    const int* __restrict__ tok, const float* __restrict__ wts,
    float* __restrict__ out)
{
  __shared__ __align__(16) ushort_t As[2 * 4096];
  __shared__ __align__(16) ushort_t Bs[2 * 4096];
  __shared__ int stok[BM];
  __shared__ float swt[BM];
  __shared__ int s_spill;

  const int tid = threadIdx.x;
  const int bid = blockIdx.x;

  int ne[E_EXP], fl[E_EXP];
#pragma unroll
  for (int i = 0; i < E_EXP; i++) {
    ne[i] = counts[i * CNT_STRIDE];
    fl[i] = ne[i] >> 7;                 // floor(n_e / 128)
  }

  const int l = tid & 63;
  const int wid = tid >> 6;             // 0..3
  const int fr = l & 15;
  const int g = l >> 4;

  if (bid < 2048) {
    // ================= BULK: 128x128 single-buffer 2-barrier ================
    int e = bid & 7;                    // = XCD (round-robin dispatch)
    int q = bid >> 3;                   // 0..255 home slot
    const int home = fl[e] * 8;
    if (q >= (home < 256 ? home : 256)) {
      // overflow tiles (n_e > 4096): claim via atomic among unused bids
      int sc[E_EXP], spill_total = 0;
#pragma unroll
      for (int i = 0; i < E_EXP; i++) {
        sc[i] = fl[i] * 8 > 256 ? fl[i] * 8 - 256 : 0;
        spill_total += sc[i];
      }
      if (spill_total == 0) return;
      if (tid == 0) s_spill = atomicAdd(&counts[520], 1);
      __syncthreads();
      int k = s_spill;
      if (k >= spill_total) return;
      int done = 0;
#pragma unroll
      for (int i = 0; i < E_EXP; i++) {
        if (!done) { if (k < sc[i]) { e = i; done = 1; } else k -= sc[i]; }
      }
      q = 256 + k;
    }
    const int mt = q >> 3;              // < fl[e] -> all 128 rows valid
    const int nt = q & 7;               // 0..7

    if (tid < BM) {
      stok[tid] = tok[e * T_TOK + mt * BM + tid];
      swt[tid] = wts[e * T_TOK + mt * BM + tid];
    }
    __syncthreads();

    // Staging: K-half = 128 rows x 4 chunks(16B) = 512 = 256 thr x 2.
    // Phys chunk p = tid + i*256 -> row p>>2, slot p&3; logical chunk =
    // slot ^ ((row>>1)&3) applied on the SOURCE address (LDS dest linear).
    const int r0 = tid >> 2;                         // 0..63
    const int cp = (tid & 3) ^ ((tid >> 3) & 3);
    const ushort_t* wTe = wT + (size_t)e * H_DIM * H_DIM;
    const ushort_t* aP0 = x_bf + (size_t)stok[r0] * H_DIM + cp * 8;
    const ushort_t* aP1 = x_bf + (size_t)stok[r0 + 64] * H_DIM + cp * 8;
    const ushort_t* bP0 = wTe + (size_t)(nt * BN + r0) * H_DIM + cp * 8;
    const ushort_t* bP1 = wTe + (size_t)(nt * BN + r0 + 64) * H_DIM + cp * 8;
    const int d0 = tid * 8;
    const int d1 = (tid + 256) * 8;

#define STAGE8(t)                                                              \
  do {                                                                         \
    GLDS16(aP0 + (t) * BK +  0, &As[0 * 4096 + d0]);                           \
    GLDS16(aP1 + (t) * BK +  0, &As[0 * 4096 + d1]);                           \
    GLDS16(aP0 + (t) * BK + 32, &As[1 * 4096 + d0]);                           \
    GLDS16(aP1 + (t) * BK + 32, &As[1 * 4096 + d1]);                           \
    GLDS16(bP0 + (t) * BK +  0, &Bs[0 * 4096 + d0]);                           \
    GLDS16(bP1 + (t) * BK +  0, &Bs[0 * 4096 + d1]);                           \
    GLDS16(bP0 + (t) * BK + 32, &Bs[1 * 4096 + d0]);                           \
    GLDS16(bP1 + (t) * BK + 32, &Bs[1 * 4096 + d1]);                           \
  } while (0)

    const int wm = wid >> 1, wn = wid & 1;      // 2x2 waves over 128x128
    const int sl = g ^ ((l >> 1) & 3);          // swizzled slot-in-half
    const int arow0 = wm * 64 + fr;
    const int brow0 = wn * 64 + fr;

    f32x4 acc[4][4] = {};

#pragma unroll 1
    for (int t = 0; t < NKT; ++t) {
      if (t) __syncthreads();       // prev compute done before overwrite
      STAGE8(t);
      __syncthreads();              // compiler emits vmcnt(0) drain + barrier
#pragma unroll
      for (int kk = 0; kk < 2; kk++) {
        bf16x8 af[4], bv[4];
#pragma unroll
        for (int mi = 0; mi < 4; mi++)
          af[mi] = *reinterpret_cast<const bf16x8*>(
              &As[kk * 4096 + (arow0 + mi * 16) * 32 + sl * 8]);
#pragma unroll
        for (int nj = 0; nj < 4; nj++)
          bv[nj] = *reinterpret_cast<const bf16x8*>(
              &Bs[kk * 4096 + (brow0 + nj * 16) * 32 + sl * 8]);
        __builtin_amdgcn_s_setprio(1);
#pragma unroll
        for (int mi = 0; mi < 4; mi++)
#pragma unroll
          for (int nj = 0; nj < 4; nj++)
            acc[mi][nj] = __builtin_amdgcn_mfma_f32_16x16x32_bf16(
                af[mi], bv[nj], acc[mi][nj], 0, 0, 0);
        __builtin_amdgcn_s_setprio(0);
      }
    }

    // Epilogue: C/D layout col=lane&15, row=(lane>>4)*4+reg.
    // f32 atomicAdd into out[token] (64B-coalesced segments, fire-and-forget).
    float bias4[4];
#pragma unroll
    for (int nj = 0; nj < 4; nj++)
      bias4[nj] = bias[e * H_DIM + nt * BN + wn * 64 + nj * 16 + fr];
#pragma unroll
    for (int mi = 0; mi < 4; mi++) {
      const int rr0 = wm * 64 + mi * 16 + g * 4;
#pragma unroll
      for (int r = 0; r < 4; r++) {
        const int row = rr0 + r;
        const float wgt = swt[row];
        float* orow = out + (size_t)stok[row] * H_DIM;
#pragma unroll
        for (int nj = 0; nj < 4; nj++) {
          const int n = nt * BN + wn * 64 + nj * 16 + fr;
          atomicAdd(&orow[n], wgt * (acc[mi][nj][r] + bias4[nj]));
        }
      }
    }
  } else {
    // ============ TAIL: 64x128 single-buffer 2-barrier ======================
    const int e = bid & 7;              // = XCD, best-effort pinning
    const int tq = (bid - 2048) >> 3;   // 0..31
    const int rem = ne[e] - (fl[e] << 7);
    const int tcnt = (rem + 63) >> 6;   // 64-row tail tiles, 0..2
    if (tq >= tcnt * 8) return;
    const int mtt = tq >> 3;            // 0..1
    const int ntt = tq & 7;             // 0..7 (128-wide N-tiles)
    const int row0 = (fl[e] << 7) + mtt * 64;
    int valid = ne[e] - row0; if (valid > 64) valid = 64;

    if (tid < 64) {
      int slot = row0 + tid;
      if (slot >= ne[e]) slot = ne[e] - 1;   // clamp; masked on store
      stok[tid] = tok[e * T_TOK + slot];
      swt[tid] = wts[e * T_TOK + slot];
    }
    __syncthreads();

    // A 64x64 = 512 chunks (2/thr), B 128x64 = 1024 chunks (4/thr).
    // Logical chunk = (tid&7) ^ (row&7) (full 3-bit row-XOR, verified).
    const ushort_t* wTe = wT + (size_t)e * H_DIM * H_DIM;
    const int trow = tid >> 3;                       // 0..31
    const int tlc = (tid & 7) ^ (trow & 7);
    const ushort_t* taS0 = x_bf + (size_t)stok[trow] * H_DIM + tlc * 8;
    const ushort_t* taS1 = x_bf + (size_t)stok[trow + 32] * H_DIM + tlc * 8;
    const ushort_t* tbS0 = wTe + (size_t)(ntt * 128 + trow) * H_DIM + tlc * 8;
    const ushort_t* tbS1 = tbS0 + (size_t)32 * H_DIM;
    const ushort_t* tbS2 = tbS0 + (size_t)64 * H_DIM;
    const ushort_t* tbS3 = tbS0 + (size_t)96 * H_DIM;

#define TSTAGE1(t)                                                             \
  do {                                                                         \
    GLDS16(taS0 + (t) * BK, &As[tid * 8]);                                     \
    GLDS16(taS1 + (t) * BK, &As[(tid + 256) * 8]);                             \
    GLDS16(tbS0 + (t) * BK, &Bs[tid * 8]);                                     \
    GLDS16(tbS1 + (t) * BK, &Bs[(tid + 256) * 8]);                             \
    GLDS16(tbS2 + (t) * BK, &Bs[(tid + 512) * 8]);                             \
    GLDS16(tbS3 + (t) * BK, &Bs[(tid + 768) * 8]);                             \
  } while (0)

    const int tph0 = (g ^ (fr & 7)) * 8;             // phys chunk, kk=0
    const int tph1 = ((4 ^ g) ^ (fr & 7)) * 8;       // kk=1

    f32x4 tacc[2][4] = {};

#pragma unroll 1
    for (int t = 0; t < NKT; ++t) {
      if (t) __syncthreads();
      TSTAGE1(t);
      __syncthreads();
#pragma unroll
      for (int kk = 0; kk < 2; kk++) {
        const int ph = kk ? tph1 : tph0;
#pragma unroll
        for (int nf = 0; nf < 2; nf++) {
          const bf16x8 tbv = *reinterpret_cast<const bf16x8*>(
              &Bs[(wid * 32 + nf * 16 + fr) * 64 + ph]);
#pragma unroll
          for (int mi = 0; mi < 4; mi++) {
            const bf16x8 tav = *reinterpret_cast<const bf16x8*>(
                &As[(mi * 16 + fr) * 64 + ph]);
            tacc[nf][mi] = __builtin_amdgcn_mfma_f32_16x16x32_bf16(
                tav, tbv, tacc[nf][mi], 0, 0, 0);
          }
        }
      }
    }

    // Epilogue: f32 atomicAdd into out[token]; clamped rows masked.
#pragma unroll
    for (int nf = 0; nf < 2; nf++) {
      const int ncol = ntt * 128 + wid * 32 + nf * 16 + fr;
      const float bs = bias[e * H_DIM + ncol];
#pragma unroll
      for (int mi = 0; mi < 4; mi++) {
        const int rb = mi * 16 + g * 4;
#pragma unroll
        for (int r = 0; r < 4; r++) {
          const int row = rb + r;
          if (row < valid) {
            float* orow = out + (size_t)stok[row] * H_DIM;
            atomicAdd(&orow[ncol], swt[row] * (tacc[nf][mi][r] + bs));
          }
        }
      }
    }
  }
}

extern "C" void kernel_launch(void* const* d_in, const int* in_sizes, int n_in,
                              void* d_out, int out_size, void* d_ws, size_t ws_size,
                              hipStream_t stream)
{
  const float* x  = (const float*)d_in[0];
  const float* gw = (const float*)d_in[1];
  const float* gb = (const float*)d_in[2];
  const float* ew = (const float*)d_in[3];
  const float* eb = (const float*)d_in[4];

  float* out = (float*)d_out;
  float* out_final = out;                                  // [T,H] f32
  float* out_idx   = out + (size_t)T_TOK * H_DIM;          // [T,2] as f32
  float* out_probs = out_idx + (size_t)T_TOK * 2;          // [T,E] f32

  char* ws = (char*)d_ws;
  size_t off = 0;
  int*      counts  = (int*)(ws + off); off += 4096;
  int*      tok     = (int*)(ws + off); off += (size_t)E_EXP * T_TOK * 4;
  float*    wts     = (float*)(ws + off); off += (size_t)E_EXP * T_TOK * 4;
  ushort_t* x_bf    = (ushort_t*)(ws + off); off += (size_t)T_TOK * H_DIM * 2;
  ushort_t* wT      = (ushort_t*)(ws + off); off += (size_t)E_EXP * H_DIM * H_DIM * 2;
  // total ~49 MB of d_ws

  hipMemsetAsync(counts, 0, 4096, stream);   // zeroes counts + spill queue

  router_transpose<<<RBLOCKS + TP_BLOCKS, 256, 0, stream>>>(
      x, gw, gb, ew, out_final, out_idx, out_probs, counts, tok, wts, x_bf, wT);
  moe_gemm<<<NWG_G, 256, 0, stream>>>(x_bf, wT, eb, counts, tok, wts, out_final);
}

// Round 14
// 93.722 us; speedup vs baseline: 1.3289x; 1.3289x over previous
//
#include <hip/hip_runtime.h>
#include <hip/hip_bf16.h>
#include <stdint.h>

typedef unsigned short ushort_t;
typedef __bf16 bf16x8 __attribute__((ext_vector_type(8)));
typedef float f32x4 __attribute__((ext_vector_type(4)));

#define T_TOK 8192
#define H_DIM 1024
#define E_EXP 8
#define BM 128
#define BN 128
#define BK 64
#define NKT (H_DIM / BK)               // 16
#define NWG_G 2304                     // 2048 bulk slots + 256 tail slots

#define CNT_STRIDE 64
#define RTOK 32
#define RBLOCKS (T_TOK / RTOK)         // 256
#define TP_BLOCKS ((H_DIM / 32) * (H_DIM / 32) * E_EXP)  // 8192

static __device__ __forceinline__ ushort_t f2bf(float f) {
  union { float f; uint32_t u; } c; c.f = f;
  uint32_t u = c.u;
  uint32_t r = u + 0x7FFFu + ((u >> 16) & 1u);  // RNE
  return (ushort_t)(r >> 16);
}

// ---- Fused: router (blocks 0..255) + expert_w transpose (blocks 256..) -----
// Router writes x_bf (single bf16 copy) during the logits pass; tok[e*T+p]
// stores token*2+k so the GEMM epilogue writes token-major y[T][2][H] and
// combine needs no slotmap.
__global__ __launch_bounds__(256) void router_transpose(
    const float* __restrict__ x, const float* __restrict__ gw,
    const float* __restrict__ gb, const float* __restrict__ ew,
    float* __restrict__ out_idx, float* __restrict__ out_probs,
    int* __restrict__ counts, int* __restrict__ tok, float* __restrict__ wts,
    ushort_t* __restrict__ x_bf, ushort_t* __restrict__ wT)
{
  __shared__ int   sm_eid[RTOK * 2];
  __shared__ float sm_wt[RTOK * 2];
  __shared__ int   lcnt[E_EXP], lbase[E_EXP], lpos[E_EXP];
  __shared__ float tile[32][33];

  const int tid = threadIdx.x;

  if (blockIdx.x >= RBLOCKS) {
    // ---------------- transpose: ew [E,K,N] f32 -> wT [E,N,K] bf16 ----------
    const int tb = blockIdx.x - RBLOCKS;
    const int e = tb >> 10;
    const int n0 = (tb & 31) * 32, k0 = ((tb >> 5) & 31) * 32;
    const float* we = ew + (size_t)e * H_DIM * H_DIM;
    ushort_t* wTe = wT + (size_t)e * H_DIM * H_DIM;
    const int tx = tid & 31, ty = tid >> 5;  // 32 x 8
#pragma unroll
    for (int i = 0; i < 4; i++)
      tile[ty + 8 * i][tx] = we[(size_t)(k0 + ty + 8 * i) * H_DIM + n0 + tx];
    __syncthreads();
#pragma unroll
    for (int i = 0; i < 4; i++)
      wTe[(size_t)(n0 + ty + 8 * i) * H_DIM + k0 + tx] = f2bf(tile[tx][ty + 8 * i]);
    return;
  }

  // ------------------------------- router -----------------------------------
  const int wave = tid >> 6, l = tid & 63;
  if (tid < E_EXP) { lcnt[tid] = 0; lpos[tid] = 0; }
  __syncthreads();

  const int t0 = blockIdx.x * RTOK;
  for (int it = 0; it < RTOK / 4; it++) {
    const int lt = wave * (RTOK / 4) + it;
    const int t = t0 + lt;
    const float* xt = x + (size_t)t * H_DIM;
    float acc[E_EXP];
#pragma unroll
    for (int e = 0; e < E_EXP; e++) acc[e] = 0.f;
#pragma unroll
    for (int i = 0; i < 4; i++) {
      const int h = (i * 64 + l) * 4;
      const float4 xv = *reinterpret_cast<const float4*>(xt + h);
      ushort4 b;
      b.x = f2bf(xv.x); b.y = f2bf(xv.y); b.z = f2bf(xv.z); b.w = f2bf(xv.w);
      *reinterpret_cast<ushort4*>(x_bf + (size_t)t * H_DIM + h) = b;
#pragma unroll
      for (int e = 0; e < E_EXP; e++) {
        const float4 g = *reinterpret_cast<const float4*>(gw + e * H_DIM + h);
        acc[e] += xv.x * g.x + xv.y * g.y + xv.z * g.z + xv.w * g.w;
      }
    }
#pragma unroll
    for (int e = 0; e < E_EXP; e++) {
      float v = acc[e];
#pragma unroll
      for (int off = 32; off; off >>= 1) v += __shfl_xor(v, off);
      acc[e] = v;
    }
    if (l == 0) {
      float lg[E_EXP], pb[E_EXP];
      float m = -1e30f;
#pragma unroll
      for (int e = 0; e < E_EXP; e++) { lg[e] = acc[e] + gb[e]; m = fmaxf(m, lg[e]); }
      float s = 0.f;
#pragma unroll
      for (int e = 0; e < E_EXP; e++) { pb[e] = expf(lg[e] - m); s += pb[e]; }
      const float inv = 1.f / s;
#pragma unroll
      for (int e = 0; e < E_EXP; e++) {
        pb[e] *= inv;
        out_probs[(size_t)t * E_EXP + e] = pb[e];
      }
      int i0 = 0; float p0 = pb[0];
#pragma unroll
      for (int e = 1; e < E_EXP; e++) if (pb[e] > p0) { p0 = pb[e]; i0 = e; }
      int i1 = -1; float p1 = -1.f;
#pragma unroll
      for (int e = 0; e < E_EXP; e++) if (e != i0 && pb[e] > p1) { p1 = pb[e]; i1 = e; }
      out_idx[(size_t)t * 2 + 0] = (float)i0;
      out_idx[(size_t)t * 2 + 1] = (float)i1;
      const float rn = 1.f / (p0 + p1);
      sm_eid[lt * 2 + 0] = i0; sm_wt[lt * 2 + 0] = p0 * rn;
      sm_eid[lt * 2 + 1] = i1; sm_wt[lt * 2 + 1] = p1 * rn;
    }
  }
  __syncthreads();

  if (tid < RTOK * 2) atomicAdd(&lcnt[sm_eid[tid]], 1);
  __syncthreads();
  if (tid < E_EXP) lbase[tid] = atomicAdd(&counts[tid * CNT_STRIDE], lcnt[tid]);
  __syncthreads();
  if (tid < RTOK * 2) {
    const int e = sm_eid[tid];
    const int p = lbase[e] + atomicAdd(&lpos[e], 1);
    const int dst = e * T_TOK + p;
    tok[dst] = (t0 + (tid >> 1)) * 2 + (tid & 1);   // token*2 + k
    wts[dst] = sm_wt[tid];
  }
}

// ------------------- Grouped GEMM -- m97/m103 structure ---------------------
// 128x128 tile, BK=64, 256 threads (2x2 waves), SINGLE-buffered 32 KiB LDS,
// plain 2-barrier loop, 3 blocks/CU (cross-block overlap hides the barrier
// drain, m114; R11 measured 53.6 us at (256,3), 0 conflicts).
// R14: revert R12's (256,4) -> (256,3) (R12's only gemm delta vs R11 besides
// the gather; (256,4) was occupancy-null and may constrain regalloc).
//   bid 0..2047   : bulk 128x128 tile (slot bid>>3, 0..255) of expert bid&7.
//   bid 2048..2303: tail 64x128 tile of expert bid&7.
#define GLDS16(gp, lp)                                                         \
  __builtin_amdgcn_global_load_lds(                                            \
      (const __attribute__((address_space(1))) void*)(gp),                     \
      (__attribute__((address_space(3))) void*)(lp), 16, 0, 0)

__global__ __launch_bounds__(256, 3) void moe_gemm(
    const ushort_t* __restrict__ x_bf, const ushort_t* __restrict__ wT,
    const float* __restrict__ bias, int* __restrict__ counts,
    const int* __restrict__ tok, const float* __restrict__ wts,
    ushort_t* __restrict__ y)
{
  __shared__ __align__(16) ushort_t As[2 * 4096];
  __shared__ __align__(16) ushort_t Bs[2 * 4096];
  __shared__ int stok[BM];
  __shared__ float swt[BM];
  __shared__ int s_spill;

  const int tid = threadIdx.x;
  const int bid = blockIdx.x;

  int ne[E_EXP], fl[E_EXP];
#pragma unroll
  for (int i = 0; i < E_EXP; i++) {
    ne[i] = counts[i * CNT_STRIDE];
    fl[i] = ne[i] >> 7;                 // floor(n_e / 128)
  }

  const int l = tid & 63;
  const int wid = tid >> 6;             // 0..3
  const int fr = l & 15;
  const int g = l >> 4;

  if (bid < 2048) {
    // ================= BULK: 128x128 single-buffer 2-barrier ================
    int e = bid & 7;                    // = XCD (round-robin dispatch)
    int q = bid >> 3;                   // 0..255 home slot
    const int home = fl[e] * 8;
    if (q >= (home < 256 ? home : 256)) {
      // overflow tiles (n_e > 4096): claim via atomic among unused bids
      int sc[E_EXP], spill_total = 0;
#pragma unroll
      for (int i = 0; i < E_EXP; i++) {
        sc[i] = fl[i] * 8 > 256 ? fl[i] * 8 - 256 : 0;
        spill_total += sc[i];
      }
      if (spill_total == 0) return;
      if (tid == 0) s_spill = atomicAdd(&counts[520], 1);
      __syncthreads();
      int k = s_spill;
      if (k >= spill_total) return;
      int done = 0;
#pragma unroll
      for (int i = 0; i < E_EXP; i++) {
        if (!done) { if (k < sc[i]) { e = i; done = 1; } else k -= sc[i]; }
      }
      q = 256 + k;
    }
    const int mt = q >> 3;              // < fl[e] -> all 128 rows valid
    const int nt = q & 7;               // 0..7

    if (tid < BM) {
      stok[tid] = tok[e * T_TOK + mt * BM + tid];   // token*2+k
      swt[tid] = wts[e * T_TOK + mt * BM + tid];
    }
    __syncthreads();

    // Staging: K-half = 128 rows x 4 chunks(16B) = 512 = 256 thr x 2.
    // Phys chunk p = tid + i*256 -> row p>>2, slot p&3; logical chunk =
    // slot ^ ((row>>1)&3) applied on the SOURCE address (LDS dest linear).
    const int r0 = tid >> 2;                         // 0..63
    const int cp = (tid & 3) ^ ((tid >> 3) & 3);
    const ushort_t* wTe = wT + (size_t)e * H_DIM * H_DIM;
    const ushort_t* aP0 = x_bf + (size_t)(stok[r0] >> 1) * H_DIM + cp * 8;
    const ushort_t* aP1 = x_bf + (size_t)(stok[r0 + 64] >> 1) * H_DIM + cp * 8;
    const ushort_t* bP0 = wTe + (size_t)(nt * BN + r0) * H_DIM + cp * 8;
    const ushort_t* bP1 = wTe + (size_t)(nt * BN + r0 + 64) * H_DIM + cp * 8;
    const int d0 = tid * 8;
    const int d1 = (tid + 256) * 8;

#define STAGE8(t)                                                              \
  do {                                                                         \
    GLDS16(aP0 + (t) * BK +  0, &As[0 * 4096 + d0]);                           \
    GLDS16(aP1 + (t) * BK +  0, &As[0 * 4096 + d1]);                           \
    GLDS16(aP0 + (t) * BK + 32, &As[1 * 4096 + d0]);                           \
    GLDS16(aP1 + (t) * BK + 32, &As[1 * 4096 + d1]);                           \
    GLDS16(bP0 + (t) * BK +  0, &Bs[0 * 4096 + d0]);                           \
    GLDS16(bP1 + (t) * BK +  0, &Bs[0 * 4096 + d1]);                           \
    GLDS16(bP0 + (t) * BK + 32, &Bs[1 * 4096 + d0]);                           \
    GLDS16(bP1 + (t) * BK + 32, &Bs[1 * 4096 + d1]);                           \
  } while (0)

    const int wm = wid >> 1, wn = wid & 1;      // 2x2 waves over 128x128
    const int sl = g ^ ((l >> 1) & 3);          // swizzled slot-in-half
    const int arow0 = wm * 64 + fr;
    const int brow0 = wn * 64 + fr;

    f32x4 acc[4][4] = {};

#pragma unroll 1
    for (int t = 0; t < NKT; ++t) {
      if (t) __syncthreads();       // prev compute done before overwrite
      STAGE8(t);
      __syncthreads();              // compiler emits vmcnt(0) drain + barrier
#pragma unroll
      for (int kk = 0; kk < 2; kk++) {
        bf16x8 af[4], bv[4];
#pragma unroll
        for (int mi = 0; mi < 4; mi++)
          af[mi] = *reinterpret_cast<const bf16x8*>(
              &As[kk * 4096 + (arow0 + mi * 16) * 32 + sl * 8]);
#pragma unroll
        for (int nj = 0; nj < 4; nj++)
          bv[nj] = *reinterpret_cast<const bf16x8*>(
              &Bs[kk * 4096 + (brow0 + nj * 16) * 32 + sl * 8]);
        __builtin_amdgcn_s_setprio(1);
#pragma unroll
        for (int mi = 0; mi < 4; mi++)
#pragma unroll
          for (int nj = 0; nj < 4; nj++)
            acc[mi][nj] = __builtin_amdgcn_mfma_f32_16x16x32_bf16(
                af[mi], bv[nj], acc[mi][nj], 0, 0, 0);
        __builtin_amdgcn_s_setprio(0);
      }
    }

    // Epilogue: C/D layout col=lane&15, row=(lane>>4)*4+reg. Token-major y.
    float bias4[4];
#pragma unroll
    for (int nj = 0; nj < 4; nj++)
      bias4[nj] = bias[e * H_DIM + nt * BN + wn * 64 + nj * 16 + fr];
#pragma unroll
    for (int mi = 0; mi < 4; mi++) {
      const int rr0 = wm * 64 + mi * 16 + g * 4;
#pragma unroll
      for (int r = 0; r < 4; r++) {
        const int row = rr0 + r;
        const float wgt = swt[row];
        ushort_t* yr = y + (size_t)stok[row] * H_DIM;
#pragma unroll
        for (int nj = 0; nj < 4; nj++) {
          const int n = nt * BN + wn * 64 + nj * 16 + fr;
          yr[n] = f2bf(wgt * (acc[mi][nj][r] + bias4[nj]));
        }
      }
    }
  } else {
    // ============ TAIL: 64x128 single-buffer 2-barrier ======================
    const int e = bid & 7;              // = XCD, best-effort pinning
    const int tq = (bid - 2048) >> 3;   // 0..31
    const int rem = ne[e] - (fl[e] << 7);
    const int tcnt = (rem + 63) >> 6;   // 64-row tail tiles, 0..2
    if (tq >= tcnt * 8) return;
    const int mtt = tq >> 3;            // 0..1
    const int ntt = tq & 7;             // 0..7 (128-wide N-tiles)
    const int row0 = (fl[e] << 7) + mtt * 64;
    int valid = ne[e] - row0; if (valid > 64) valid = 64;

    if (tid < 64) {
      int slot = row0 + tid;
      if (slot >= ne[e]) slot = ne[e] - 1;   // clamp; masked on store
      stok[tid] = tok[e * T_TOK + slot];
      swt[tid] = wts[e * T_TOK + slot];
    }
    __syncthreads();

    // A 64x64 = 512 chunks (2/thr), B 128x64 = 1024 chunks (4/thr).
    // Logical chunk = (tid&7) ^ (row&7) (full 3-bit row-XOR, verified).
    const ushort_t* wTe = wT + (size_t)e * H_DIM * H_DIM;
    const int trow = tid >> 3;                       // 0..31
    const int tlc = (tid & 7) ^ (trow & 7);
    const ushort_t* taS0 = x_bf + (size_t)(stok[trow] >> 1) * H_DIM + tlc * 8;
    const ushort_t* taS1 = x_bf + (size_t)(stok[trow + 32] >> 1) * H_DIM + tlc * 8;
    const ushort_t* tbS0 = wTe + (size_t)(ntt * 128 + trow) * H_DIM + tlc * 8;
    const ushort_t* tbS1 = tbS0 + (size_t)32 * H_DIM;
    const ushort_t* tbS2 = tbS0 + (size_t)64 * H_DIM;
    const ushort_t* tbS3 = tbS0 + (size_t)96 * H_DIM;

#define TSTAGE1(t)                                                             \
  do {                                                                         \
    GLDS16(taS0 + (t) * BK, &As[tid * 8]);                                     \
    GLDS16(taS1 + (t) * BK, &As[(tid + 256) * 8]);                             \
    GLDS16(tbS0 + (t) * BK, &Bs[tid * 8]);                                     \
    GLDS16(tbS1 + (t) * BK, &Bs[(tid + 256) * 8]);                             \
    GLDS16(tbS2 + (t) * BK, &Bs[(tid + 512) * 8]);                             \
    GLDS16(tbS3 + (t) * BK, &Bs[(tid + 768) * 8]);                             \
  } while (0)

    const int tph0 = (g ^ (fr & 7)) * 8;             // phys chunk, kk=0
    const int tph1 = ((4 ^ g) ^ (fr & 7)) * 8;       // kk=1

    f32x4 tacc[2][4] = {};

#pragma unroll 1
    for (int t = 0; t < NKT; ++t) {
      if (t) __syncthreads();
      TSTAGE1(t);
      __syncthreads();
#pragma unroll
      for (int kk = 0; kk < 2; kk++) {
        const int ph = kk ? tph1 : tph0;
#pragma unroll
        for (int nf = 0; nf < 2; nf++) {
          const bf16x8 tbv = *reinterpret_cast<const bf16x8*>(
              &Bs[(wid * 32 + nf * 16 + fr) * 64 + ph]);
#pragma unroll
          for (int mi = 0; mi < 4; mi++) {
            const bf16x8 tav = *reinterpret_cast<const bf16x8*>(
                &As[(mi * 16 + fr) * 64 + ph]);
            tacc[nf][mi] = __builtin_amdgcn_mfma_f32_16x16x32_bf16(
                tav, tbv, tacc[nf][mi], 0, 0, 0);
          }
        }
      }
    }

    // Epilogue (token-major y)
#pragma unroll
    for (int nf = 0; nf < 2; nf++) {
      const int ncol = ntt * 128 + wid * 32 + nf * 16 + fr;
      const float bs = bias[e * H_DIM + ncol];
#pragma unroll
      for (int mi = 0; mi < 4; mi++) {
        const int rb = mi * 16 + g * 4;
#pragma unroll
        for (int r = 0; r < 4; r++) {
          const int row = rb + r;
          if (row < valid) {
            ushort_t* yr = y + (size_t)stok[row] * H_DIM;
            yr[ncol] = f2bf(swt[row] * (tacc[nf][mi][r] + bs));
          }
        }
      }
    }
  }
}

// ------------- combine: out[t] = y[t*2] + y[t*2+1] (token-major) ------------
__global__ __launch_bounds__(256) void combine_kernel(
    const ushort_t* __restrict__ y, float* __restrict__ out)
{
  const int t = blockIdx.x;
  const ushort_t* r0 = y + (size_t)(t * 2) * H_DIM;
  const ushort_t* r1 = r0 + H_DIM;
  float* o = out + (size_t)t * H_DIM;
  const int h = threadIdx.x * 4;
  const ushort4 u0 = *reinterpret_cast<const ushort4*>(r0 + h);
  const ushort4 u1 = *reinterpret_cast<const ushort4*>(r1 + h);
  float4 v;
  union { uint32_t u; float f; } c;
  c.u = (uint32_t)u0.x << 16; v.x = c.f; c.u = (uint32_t)u1.x << 16; v.x += c.f;
  c.u = (uint32_t)u0.y << 16; v.y = c.f; c.u = (uint32_t)u1.y << 16; v.y += c.f;
  c.u = (uint32_t)u0.z << 16; v.z = c.f; c.u = (uint32_t)u1.z << 16; v.z += c.f;
  c.u = (uint32_t)u0.w << 16; v.w = c.f; c.u = (uint32_t)u1.w << 16; v.w += c.f;
  *reinterpret_cast<float4*>(o + h) = v;
}

extern "C" void kernel_launch(void* const* d_in, const int* in_sizes, int n_in,
                              void* d_out, int out_size, void* d_ws, size_t ws_size,
                              hipStream_t stream)
{
  const float* x  = (const float*)d_in[0];
  const float* gw = (const float*)d_in[1];
  const float* gb = (const float*)d_in[2];
  const float* ew = (const float*)d_in[3];
  const float* eb = (const float*)d_in[4];

  float* out = (float*)d_out;
  float* out_final = out;                                  // [T,H] f32
  float* out_idx   = out + (size_t)T_TOK * H_DIM;          // [T,2] as f32
  float* out_probs = out_idx + (size_t)T_TOK * 2;          // [T,E] f32

  char* ws = (char*)d_ws;
  size_t off = 0;
  int*      counts  = (int*)(ws + off); off += 4096;
  int*      tok     = (int*)(ws + off); off += (size_t)E_EXP * T_TOK * 4;
  float*    wts     = (float*)(ws + off); off += (size_t)E_EXP * T_TOK * 4;
  ushort_t* x_bf    = (ushort_t*)(ws + off); off += (size_t)T_TOK * H_DIM * 2;
  ushort_t* wT      = (ushort_t*)(ws + off); off += (size_t)E_EXP * H_DIM * H_DIM * 2;
  ushort_t* y       = (ushort_t*)(ws + off); off += (size_t)T_TOK * 2 * H_DIM * 2;
  // total ~82 MB of d_ws

  hipMemsetAsync(counts, 0, 4096, stream);   // zeroes counts + spill queue

  router_transpose<<<RBLOCKS + TP_BLOCKS, 256, 0, stream>>>(
      x, gw, gb, ew, out_idx, out_probs, counts, tok, wts, x_bf, wT);
  moe_gemm<<<NWG_G, 256, 0, stream>>>(x_bf, wT, eb, counts, tok, wts, y);
  combine_kernel<<<T_TOK, 256, 0, stream>>>(y, out_final);
}

// Round 15
// 91.716 us; speedup vs baseline: 1.3579x; 1.0219x over previous
//
#include <hip/hip_runtime.h>
#include <hip/hip_bf16.h>
#include <stdint.h>

typedef unsigned short ushort_t;
typedef __bf16 bf16x8 __attribute__((ext_vector_type(8)));
typedef float f32x4 __attribute__((ext_vector_type(4)));

#define T_TOK 8192
#define H_DIM 1024
#define E_EXP 8
#define BM 128
#define BN 128
#define BK 64
#define NKT (H_DIM / BK)               // 16
#define NWG_G 2304                     // 256 tail slots + 2048 bulk slots

#define CNT_STRIDE 64
#define RTOK 32
#define RBLOCKS (T_TOK / RTOK)         // 256
#define TP_BLOCKS ((H_DIM / 32) * (H_DIM / 32) * E_EXP)  // 8192

static __device__ __forceinline__ ushort_t f2bf(float f) {
  union { float f; uint32_t u; } c; c.f = f;
  uint32_t u = c.u;
  uint32_t r = u + 0x7FFFu + ((u >> 16) & 1u);  // RNE
  return (ushort_t)(r >> 16);
}

// ---- Fused: router (blocks 0..255) + expert_w transpose (blocks 256..) -----
__global__ __launch_bounds__(256) void router_transpose(
    const float* __restrict__ x, const float* __restrict__ gw,
    const float* __restrict__ gb, const float* __restrict__ ew,
    float* __restrict__ out_idx, float* __restrict__ out_probs,
    int* __restrict__ counts, int* __restrict__ tok, float* __restrict__ wts,
    ushort_t* __restrict__ x_bf, ushort_t* __restrict__ wT)
{
  __shared__ int   sm_eid[RTOK * 2];
  __shared__ float sm_wt[RTOK * 2];
  __shared__ int   lcnt[E_EXP], lbase[E_EXP], lpos[E_EXP];
  __shared__ float tile[32][33];

  const int tid = threadIdx.x;

  if (blockIdx.x >= RBLOCKS) {
    // ---------------- transpose: ew [E,K,N] f32 -> wT [E,N,K] bf16 ----------
    const int tb = blockIdx.x - RBLOCKS;
    const int e = tb >> 10;
    const int n0 = (tb & 31) * 32, k0 = ((tb >> 5) & 31) * 32;
    const float* we = ew + (size_t)e * H_DIM * H_DIM;
    ushort_t* wTe = wT + (size_t)e * H_DIM * H_DIM;
    const int tx = tid & 31, ty = tid >> 5;  // 32 x 8
#pragma unroll
    for (int i = 0; i < 4; i++)
      tile[ty + 8 * i][tx] = we[(size_t)(k0 + ty + 8 * i) * H_DIM + n0 + tx];
    __syncthreads();
#pragma unroll
    for (int i = 0; i < 4; i++)
      wTe[(size_t)(n0 + ty + 8 * i) * H_DIM + k0 + tx] = f2bf(tile[tx][ty + 8 * i]);
    return;
  }

  // ------------------------------- router -----------------------------------
  const int wave = tid >> 6, l = tid & 63;
  if (tid < E_EXP) { lcnt[tid] = 0; lpos[tid] = 0; }
  __syncthreads();

  const int t0 = blockIdx.x * RTOK;
  for (int it = 0; it < RTOK / 4; it++) {
    const int lt = wave * (RTOK / 4) + it;
    const int t = t0 + lt;
    const float* xt = x + (size_t)t * H_DIM;
    float acc[E_EXP];
#pragma unroll
    for (int e = 0; e < E_EXP; e++) acc[e] = 0.f;
#pragma unroll
    for (int i = 0; i < 4; i++) {
      const int h = (i * 64 + l) * 4;
      const float4 xv = *reinterpret_cast<const float4*>(xt + h);
      ushort4 b;
      b.x = f2bf(xv.x); b.y = f2bf(xv.y); b.z = f2bf(xv.z); b.w = f2bf(xv.w);
      *reinterpret_cast<ushort4*>(x_bf + (size_t)t * H_DIM + h) = b;
#pragma unroll
      for (int e = 0; e < E_EXP; e++) {
        const float4 g = *reinterpret_cast<const float4*>(gw + e * H_DIM + h);
        acc[e] += xv.x * g.x + xv.y * g.y + xv.z * g.z + xv.w * g.w;
      }
    }
#pragma unroll
    for (int e = 0; e < E_EXP; e++) {
      float v = acc[e];
#pragma unroll
      for (int off = 32; off; off >>= 1) v += __shfl_xor(v, off);
      acc[e] = v;
    }
    if (l == 0) {
      float lg[E_EXP], pb[E_EXP];
      float m = -1e30f;
#pragma unroll
      for (int e = 0; e < E_EXP; e++) { lg[e] = acc[e] + gb[e]; m = fmaxf(m, lg[e]); }
      float s = 0.f;
#pragma unroll
      for (int e = 0; e < E_EXP; e++) { pb[e] = expf(lg[e] - m); s += pb[e]; }
      const float inv = 1.f / s;
#pragma unroll
      for (int e = 0; e < E_EXP; e++) {
        pb[e] *= inv;
        out_probs[(size_t)t * E_EXP + e] = pb[e];
      }
      int i0 = 0; float p0 = pb[0];
#pragma unroll
      for (int e = 1; e < E_EXP; e++) if (pb[e] > p0) { p0 = pb[e]; i0 = e; }
      int i1 = -1; float p1 = -1.f;
#pragma unroll
      for (int e = 0; e < E_EXP; e++) if (e != i0 && pb[e] > p1) { p1 = pb[e]; i1 = e; }
      out_idx[(size_t)t * 2 + 0] = (float)i0;
      out_idx[(size_t)t * 2 + 1] = (float)i1;
      const float rn = 1.f / (p0 + p1);
      sm_eid[lt * 2 + 0] = i0; sm_wt[lt * 2 + 0] = p0 * rn;
      sm_eid[lt * 2 + 1] = i1; sm_wt[lt * 2 + 1] = p1 * rn;
    }
  }
  __syncthreads();

  if (tid < RTOK * 2) atomicAdd(&lcnt[sm_eid[tid]], 1);
  __syncthreads();
  if (tid < E_EXP) lbase[tid] = atomicAdd(&counts[tid * CNT_STRIDE], lcnt[tid]);
  __syncthreads();
  if (tid < RTOK * 2) {
    const int e = sm_eid[tid];
    const int p = lbase[e] + atomicAdd(&lpos[e], 1);
    const int dst = e * T_TOK + p;
    tok[dst] = (t0 + (tid >> 1)) * 2 + (tid & 1);   // token*2 + k
    wts[dst] = sm_wt[tid];
  }
}

// ------------------- Grouped GEMM -- m97/m103 structure ---------------------
// 128x128 tile, BK=64, 256 threads (2x2 waves), SINGLE-buffered 32 KiB LDS,
// plain 2-barrier loop, ~3 blocks/CU (cross-block overlap hides the barrier
// drain, m114). R15: epilogue re-staged through LDS (reuse As/Bs) so global
// writes are 16B coalesced dwordx4 (8/thread) instead of 64 scattered 2B
// stores; tail tiles dispatched FIRST (bids 0..255) to fill CUs at t~0.
//   bid 0..255    : tail 64x128 tile of expert bid&7.
//   bid 256..2303 : bulk 128x128 tile (slot (bid-256)>>3) of expert bid&7.
#define GLDS16(gp, lp)                                                         \
  __builtin_amdgcn_global_load_lds(                                            \
      (const __attribute__((address_space(1))) void*)(gp),                     \
      (__attribute__((address_space(3))) void*)(lp), 16, 0, 0)

__global__ __launch_bounds__(256, 3) void moe_gemm(
    const ushort_t* __restrict__ x_bf, const ushort_t* __restrict__ wT,
    const float* __restrict__ bias, int* __restrict__ counts,
    const int* __restrict__ tok, const float* __restrict__ wts,
    ushort_t* __restrict__ y)
{
  __shared__ __align__(16) ushort_t As[2 * 4096];   // 16 KiB
  __shared__ __align__(16) ushort_t Bs[2 * 4096];   // 16 KiB
  __shared__ int stok[BM];
  __shared__ float swt[BM];
  __shared__ int s_spill;

  const int tid = threadIdx.x;
  const int bid = blockIdx.x;

  int ne[E_EXP], fl[E_EXP];
#pragma unroll
  for (int i = 0; i < E_EXP; i++) {
    ne[i] = counts[i * CNT_STRIDE];
    fl[i] = ne[i] >> 7;                 // floor(n_e / 128)
  }

  const int l = tid & 63;
  const int wid = tid >> 6;             // 0..3
  const int fr = l & 15;
  const int g = l >> 4;

  if (bid >= 256) {
    // ================= BULK: 128x128 single-buffer 2-barrier ================
    int e = bid & 7;                    // = XCD (round-robin; 256%8==0)
    int q = (bid - 256) >> 3;           // 0..255 home slot
    const int home = fl[e] * 8;
    if (q >= (home < 256 ? home : 256)) {
      // overflow tiles (n_e > 4096): claim via atomic among unused bids
      int sc[E_EXP], spill_total = 0;
#pragma unroll
      for (int i = 0; i < E_EXP; i++) {
        sc[i] = fl[i] * 8 > 256 ? fl[i] * 8 - 256 : 0;
        spill_total += sc[i];
      }
      if (spill_total == 0) return;
      if (tid == 0) s_spill = atomicAdd(&counts[520], 1);
      __syncthreads();
      int k = s_spill;
      if (k >= spill_total) return;
      int done = 0;
#pragma unroll
      for (int i = 0; i < E_EXP; i++) {
        if (!done) { if (k < sc[i]) { e = i; done = 1; } else k -= sc[i]; }
      }
      q = 256 + k;
    }
    const int mt = q >> 3;              // < fl[e] -> all 128 rows valid
    const int nt = q & 7;               // 0..7

    if (tid < BM) {
      stok[tid] = tok[e * T_TOK + mt * BM + tid];   // token*2+k
      swt[tid] = wts[e * T_TOK + mt * BM + tid];
    }
    __syncthreads();

    // Staging: K-half = 128 rows x 4 chunks(16B) = 512 = 256 thr x 2.
    // Phys chunk p = tid + i*256 -> row p>>2, slot p&3; logical chunk =
    // slot ^ ((row>>1)&3) applied on the SOURCE address (LDS dest linear).
    const int r0 = tid >> 2;                         // 0..63
    const int cp = (tid & 3) ^ ((tid >> 3) & 3);
    const ushort_t* wTe = wT + (size_t)e * H_DIM * H_DIM;
    const ushort_t* aP0 = x_bf + (size_t)(stok[r0] >> 1) * H_DIM + cp * 8;
    const ushort_t* aP1 = x_bf + (size_t)(stok[r0 + 64] >> 1) * H_DIM + cp * 8;
    const ushort_t* bP0 = wTe + (size_t)(nt * BN + r0) * H_DIM + cp * 8;
    const ushort_t* bP1 = wTe + (size_t)(nt * BN + r0 + 64) * H_DIM + cp * 8;
    const int d0 = tid * 8;
    const int d1 = (tid + 256) * 8;

#define STAGE8(t)                                                              \
  do {                                                                         \
    GLDS16(aP0 + (t) * BK +  0, &As[0 * 4096 + d0]);                           \
    GLDS16(aP1 + (t) * BK +  0, &As[0 * 4096 + d1]);                           \
    GLDS16(aP0 + (t) * BK + 32, &As[1 * 4096 + d0]);                           \
    GLDS16(aP1 + (t) * BK + 32, &As[1 * 4096 + d1]);                           \
    GLDS16(bP0 + (t) * BK +  0, &Bs[0 * 4096 + d0]);                           \
    GLDS16(bP1 + (t) * BK +  0, &Bs[0 * 4096 + d1]);                           \
    GLDS16(bP0 + (t) * BK + 32, &Bs[1 * 4096 + d0]);                           \
    GLDS16(bP1 + (t) * BK + 32, &Bs[1 * 4096 + d1]);                           \
  } while (0)

    const int wm = wid >> 1, wn = wid & 1;      // 2x2 waves over 128x128
    const int sl = g ^ ((l >> 1) & 3);          // swizzled slot-in-half
    const int arow0 = wm * 64 + fr;
    const int brow0 = wn * 64 + fr;

    f32x4 acc[4][4] = {};

#pragma unroll 1
    for (int t = 0; t < NKT; ++t) {
      if (t) __syncthreads();       // prev compute done before overwrite
      STAGE8(t);
      __syncthreads();              // compiler emits vmcnt(0) drain + barrier
#pragma unroll
      for (int kk = 0; kk < 2; kk++) {
        bf16x8 af[4], bv[4];
#pragma unroll
        for (int mi = 0; mi < 4; mi++)
          af[mi] = *reinterpret_cast<const bf16x8*>(
              &As[kk * 4096 + (arow0 + mi * 16) * 32 + sl * 8]);
#pragma unroll
        for (int nj = 0; nj < 4; nj++)
          bv[nj] = *reinterpret_cast<const bf16x8*>(
              &Bs[kk * 4096 + (brow0 + nj * 16) * 32 + sl * 8]);
        __builtin_amdgcn_s_setprio(1);
#pragma unroll
        for (int mi = 0; mi < 4; mi++)
#pragma unroll
          for (int nj = 0; nj < 4; nj++)
            acc[mi][nj] = __builtin_amdgcn_mfma_f32_16x16x32_bf16(
                af[mi], bv[nj], acc[mi][nj], 0, 0, 0);
        __builtin_amdgcn_s_setprio(0);
      }
    }

    // Epilogue v2: C/D layout col=lane&15, row=(lane>>4)*4+reg.
    // Stage weighted+biased bf16 into LDS (As=rows 0..63, Bs=rows 64..127),
    // then 8 coalesced 16B row-segment stores per thread into token-major y.
    __syncthreads();   // all LDS reads of the K-loop done
    float bias4[4];
#pragma unroll
    for (int nj = 0; nj < 4; nj++)
      bias4[nj] = bias[e * H_DIM + nt * BN + wn * 64 + nj * 16 + fr];
#pragma unroll
    for (int mi = 0; mi < 4; mi++) {
      const int rr0 = wm * 64 + mi * 16 + g * 4;
#pragma unroll
      for (int r = 0; r < 4; r++) {
        const int row = rr0 + r;
        const float wgt = swt[row];
#pragma unroll
        for (int nj = 0; nj < 4; nj++) {
          const int col = wn * 64 + nj * 16 + fr;
          const ushort_t v = f2bf(wgt * (acc[mi][nj][r] + bias4[nj]));
          if (row < 64) As[row * 128 + col] = v;
          else          Bs[(row - 64) * 128 + col] = v;
        }
      }
    }
    __syncthreads();
#pragma unroll
    for (int i = 0; i < 8; i++) {
      const int c = tid + i * 256;       // 0..2047
      const int row = c >> 4;            // 0..127
      const int ci = c & 15;             // 16B chunk in row
      const ushort_t* src = (row < 64) ? &As[row * 128 + ci * 8]
                                       : &Bs[(row - 64) * 128 + ci * 8];
      ushort_t* dst = y + (size_t)stok[row] * H_DIM + nt * BN + ci * 8;
      *reinterpret_cast<int4*>(dst) = *reinterpret_cast<const int4*>(src);
    }
  } else {
    // ============ TAIL: 64x128 single-buffer 2-barrier ======================
    const int e = bid & 7;              // = XCD, best-effort pinning
    const int tq = bid >> 3;            // 0..31
    const int rem = ne[e] - (fl[e] << 7);
    const int tcnt = (rem + 63) >> 6;   // 64-row tail tiles, 0..2
    if (tq >= tcnt * 8) return;
    const int mtt = tq >> 3;            // 0..1
    const int ntt = tq & 7;             // 0..7 (128-wide N-tiles)
    const int row0 = (fl[e] << 7) + mtt * 64;
    int valid = ne[e] - row0; if (valid > 64) valid = 64;

    if (tid < 64) {
      int slot = row0 + tid;
      if (slot >= ne[e]) slot = ne[e] - 1;   // clamp; masked on store
      stok[tid] = tok[e * T_TOK + slot];
      swt[tid] = wts[e * T_TOK + slot];
    }
    __syncthreads();

    // A 64x64 = 512 chunks (2/thr), B 128x64 = 1024 chunks (4/thr).
    // Logical chunk = (tid&7) ^ (row&7) (full 3-bit row-XOR, verified).
    const ushort_t* wTe = wT + (size_t)e * H_DIM * H_DIM;
    const int trow = tid >> 3;                       // 0..31
    const int tlc = (tid & 7) ^ (trow & 7);
    const ushort_t* taS0 = x_bf + (size_t)(stok[trow] >> 1) * H_DIM + tlc * 8;
    const ushort_t* taS1 = x_bf + (size_t)(stok[trow + 32] >> 1) * H_DIM + tlc * 8;
    const ushort_t* tbS0 = wTe + (size_t)(ntt * 128 + trow) * H_DIM + tlc * 8;
    const ushort_t* tbS1 = tbS0 + (size_t)32 * H_DIM;
    const ushort_t* tbS2 = tbS0 + (size_t)64 * H_DIM;
    const ushort_t* tbS3 = tbS0 + (size_t)96 * H_DIM;

#define TSTAGE1(t)                                                             \
  do {                                                                         \
    GLDS16(taS0 + (t) * BK, &As[tid * 8]);                                     \
    GLDS16(taS1 + (t) * BK, &As[(tid + 256) * 8]);                             \
    GLDS16(tbS0 + (t) * BK, &Bs[tid * 8]);                                     \
    GLDS16(tbS1 + (t) * BK, &Bs[(tid + 256) * 8]);                             \
    GLDS16(tbS2 + (t) * BK, &Bs[(tid + 512) * 8]);                             \
    GLDS16(tbS3 + (t) * BK, &Bs[(tid + 768) * 8]);                             \
  } while (0)

    const int tph0 = (g ^ (fr & 7)) * 8;             // phys chunk, kk=0
    const int tph1 = ((4 ^ g) ^ (fr & 7)) * 8;       // kk=1

    f32x4 tacc[2][4] = {};

#pragma unroll 1
    for (int t = 0; t < NKT; ++t) {
      if (t) __syncthreads();
      TSTAGE1(t);
      __syncthreads();
#pragma unroll
      for (int kk = 0; kk < 2; kk++) {
        const int ph = kk ? tph1 : tph0;
#pragma unroll
        for (int nf = 0; nf < 2; nf++) {
          const bf16x8 tbv = *reinterpret_cast<const bf16x8*>(
              &Bs[(wid * 32 + nf * 16 + fr) * 64 + ph]);
#pragma unroll
          for (int mi = 0; mi < 4; mi++) {
            const bf16x8 tav = *reinterpret_cast<const bf16x8*>(
                &As[(mi * 16 + fr) * 64 + ph]);
            tacc[nf][mi] = __builtin_amdgcn_mfma_f32_16x16x32_bf16(
                tav, tbv, tacc[nf][mi], 0, 0, 0);
          }
        }
      }
    }

    // Epilogue v2: stage into As as [64][128] bf16, then coalesced stores.
    __syncthreads();
    float bs2[2];
#pragma unroll
    for (int nf = 0; nf < 2; nf++)
      bs2[nf] = bias[e * H_DIM + ntt * 128 + wid * 32 + nf * 16 + fr];
#pragma unroll
    for (int nf = 0; nf < 2; nf++) {
      const int col = wid * 32 + nf * 16 + fr;
#pragma unroll
      for (int mi = 0; mi < 4; mi++) {
        const int rb = mi * 16 + g * 4;
#pragma unroll
        for (int r = 0; r < 4; r++) {
          const int row = rb + r;
          As[row * 128 + col] = f2bf(swt[row] * (tacc[nf][mi][r] + bs2[nf]));
        }
      }
    }
    __syncthreads();
#pragma unroll
    for (int i = 0; i < 4; i++) {
      const int c = tid + i * 256;       // 0..1023
      const int row = c >> 4;            // 0..63
      const int ci = c & 15;
      if (row < valid) {
        ushort_t* dst = y + (size_t)stok[row] * H_DIM + ntt * 128 + ci * 8;
        *reinterpret_cast<int4*>(dst) =
            *reinterpret_cast<const int4*>(&As[row * 128 + ci * 8]);
      }
    }
  }
}

// ------------- combine: out[t] = y[t*2] + y[t*2+1] (token-major) ------------
__global__ __launch_bounds__(256) void combine_kernel(
    const ushort_t* __restrict__ y, float* __restrict__ out)
{
  const int t = blockIdx.x;
  const ushort_t* r0 = y + (size_t)(t * 2) * H_DIM;
  const ushort_t* r1 = r0 + H_DIM;
  float* o = out + (size_t)t * H_DIM;
  const int h = threadIdx.x * 4;
  const ushort4 u0 = *reinterpret_cast<const ushort4*>(r0 + h);
  const ushort4 u1 = *reinterpret_cast<const ushort4*>(r1 + h);
  float4 v;
  union { uint32_t u; float f; } c;
  c.u = (uint32_t)u0.x << 16; v.x = c.f; c.u = (uint32_t)u1.x << 16; v.x += c.f;
  c.u = (uint32_t)u0.y << 16; v.y = c.f; c.u = (uint32_t)u1.y << 16; v.y += c.f;
  c.u = (uint32_t)u0.z << 16; v.z = c.f; c.u = (uint32_t)u1.z << 16; v.z += c.f;
  c.u = (uint32_t)u0.w << 16; v.w = c.f; c.u = (uint32_t)u1.w << 16; v.w += c.f;
  *reinterpret_cast<float4*>(o + h) = v;
}

extern "C" void kernel_launch(void* const* d_in, const int* in_sizes, int n_in,
                              void* d_out, int out_size, void* d_ws, size_t ws_size,
                              hipStream_t stream)
{
  const float* x  = (const float*)d_in[0];
  const float* gw = (const float*)d_in[1];
  const float* gb = (const float*)d_in[2];
  const float* ew = (const float*)d_in[3];
  const float* eb = (const float*)d_in[4];

  float* out = (float*)d_out;
  float* out_final = out;                                  // [T,H] f32
  float* out_idx   = out + (size_t)T_TOK * H_DIM;          // [T,2] as f32
  float* out_probs = out_idx + (size_t)T_TOK * 2;          // [T,E] f32

  char* ws = (char*)d_ws;
  size_t off = 0;
  int*      counts  = (int*)(ws + off); off += 4096;
  int*      tok     = (int*)(ws + off); off += (size_t)E_EXP * T_TOK * 4;
  float*    wts     = (float*)(ws + off); off += (size_t)E_EXP * T_TOK * 4;
  ushort_t* x_bf    = (ushort_t*)(ws + off); off += (size_t)T_TOK * H_DIM * 2;
  ushort_t* wT      = (ushort_t*)(ws + off); off += (size_t)E_EXP * H_DIM * H_DIM * 2;
  ushort_t* y       = (ushort_t*)(ws + off); off += (size_t)T_TOK * 2 * H_DIM * 2;
  // total ~82 MB of d_ws

  hipMemsetAsync(counts, 0, 4096, stream);   // zeroes counts + spill queue

  router_transpose<<<RBLOCKS + TP_BLOCKS, 256, 0, stream>>>(
      x, gw, gb, ew, out_idx, out_probs, counts, tok, wts, x_bf, wT);
  moe_gemm<<<NWG_G, 256, 0, stream>>>(x_bf, wT, eb, counts, tok, wts, y);
  combine_kernel<<<T_TOK, 256, 0, stream>>>(y, out_final);
}

// Round 16
// 91.513 us; speedup vs baseline: 1.3610x; 1.0022x over previous
//
#include <hip/hip_runtime.h>
#include <hip/hip_bf16.h>
#include <stdint.h>

typedef unsigned short ushort_t;
typedef __bf16 bf16x8 __attribute__((ext_vector_type(8)));
typedef float f32x4 __attribute__((ext_vector_type(4)));

#define T_TOK 8192
#define H_DIM 1024
#define E_EXP 8
#define BM 128
#define BN 128
#define BK 64
#define NKT (H_DIM / BK)               // 16
#define NWG_G 2304                     // 256 tail slots + 2048 bulk slots

#define CNT_STRIDE 64
#define RTOK 32
#define RBLOCKS (T_TOK / RTOK)         // 256
#define TP_BLOCKS ((H_DIM / 32) * (H_DIM / 32) * E_EXP)  // 8192

static __device__ __forceinline__ ushort_t f2bf(float f) {
  union { float f; uint32_t u; } c; c.f = f;
  uint32_t u = c.u;
  uint32_t r = u + 0x7FFFu + ((u >> 16) & 1u);  // RNE
  return (ushort_t)(r >> 16);
}

// ---- Fused: router (blocks 0..255) + expert_w transpose (blocks 256..) -----
__global__ __launch_bounds__(256) void router_transpose(
    const float* __restrict__ x, const float* __restrict__ gw,
    const float* __restrict__ gb, const float* __restrict__ ew,
    float* __restrict__ out_idx, float* __restrict__ out_probs,
    int* __restrict__ counts, int* __restrict__ tok, float* __restrict__ wts,
    ushort_t* __restrict__ x_bf, ushort_t* __restrict__ wT)
{
  __shared__ int   sm_eid[RTOK * 2];
  __shared__ float sm_wt[RTOK * 2];
  __shared__ int   lcnt[E_EXP], lbase[E_EXP], lpos[E_EXP];
  __shared__ float tile[32][33];

  const int tid = threadIdx.x;

  if (blockIdx.x >= RBLOCKS) {
    // ---------------- transpose: ew [E,K,N] f32 -> wT [E,N,K] bf16 ----------
    const int tb = blockIdx.x - RBLOCKS;
    const int e = tb >> 10;
    const int n0 = (tb & 31) * 32, k0 = ((tb >> 5) & 31) * 32;
    const float* we = ew + (size_t)e * H_DIM * H_DIM;
    ushort_t* wTe = wT + (size_t)e * H_DIM * H_DIM;
    const int tx = tid & 31, ty = tid >> 5;  // 32 x 8
#pragma unroll
    for (int i = 0; i < 4; i++)
      tile[ty + 8 * i][tx] = we[(size_t)(k0 + ty + 8 * i) * H_DIM + n0 + tx];
    __syncthreads();
#pragma unroll
    for (int i = 0; i < 4; i++)
      wTe[(size_t)(n0 + ty + 8 * i) * H_DIM + k0 + tx] = f2bf(tile[tx][ty + 8 * i]);
    return;
  }

  // ------------------------------- router -----------------------------------
  const int wave = tid >> 6, l = tid & 63;
  if (tid < E_EXP) { lcnt[tid] = 0; lpos[tid] = 0; }
  __syncthreads();

  const int t0 = blockIdx.x * RTOK;
  for (int it = 0; it < RTOK / 4; it++) {
    const int lt = wave * (RTOK / 4) + it;
    const int t = t0 + lt;
    const float* xt = x + (size_t)t * H_DIM;
    float acc[E_EXP];
#pragma unroll
    for (int e = 0; e < E_EXP; e++) acc[e] = 0.f;
#pragma unroll
    for (int i = 0; i < 4; i++) {
      const int h = (i * 64 + l) * 4;
      const float4 xv = *reinterpret_cast<const float4*>(xt + h);
      ushort4 b;
      b.x = f2bf(xv.x); b.y = f2bf(xv.y); b.z = f2bf(xv.z); b.w = f2bf(xv.w);
      *reinterpret_cast<ushort4*>(x_bf + (size_t)t * H_DIM + h) = b;
#pragma unroll
      for (int e = 0; e < E_EXP; e++) {
        const float4 g = *reinterpret_cast<const float4*>(gw + e * H_DIM + h);
        acc[e] += xv.x * g.x + xv.y * g.y + xv.z * g.z + xv.w * g.w;
      }
    }
#pragma unroll
    for (int e = 0; e < E_EXP; e++) {
      float v = acc[e];
#pragma unroll
      for (int off = 32; off; off >>= 1) v += __shfl_xor(v, off);
      acc[e] = v;
    }
    if (l == 0) {
      float lg[E_EXP], pb[E_EXP];
      float m = -1e30f;
#pragma unroll
      for (int e = 0; e < E_EXP; e++) { lg[e] = acc[e] + gb[e]; m = fmaxf(m, lg[e]); }
      float s = 0.f;
#pragma unroll
      for (int e = 0; e < E_EXP; e++) { pb[e] = expf(lg[e] - m); s += pb[e]; }
      const float inv = 1.f / s;
#pragma unroll
      for (int e = 0; e < E_EXP; e++) {
        pb[e] *= inv;
        out_probs[(size_t)t * E_EXP + e] = pb[e];
      }
      int i0 = 0; float p0 = pb[0];
#pragma unroll
      for (int e = 1; e < E_EXP; e++) if (pb[e] > p0) { p0 = pb[e]; i0 = e; }
      int i1 = -1; float p1 = -1.f;
#pragma unroll
      for (int e = 0; e < E_EXP; e++) if (e != i0 && pb[e] > p1) { p1 = pb[e]; i1 = e; }
      out_idx[(size_t)t * 2 + 0] = (float)i0;
      out_idx[(size_t)t * 2 + 1] = (float)i1;
      const float rn = 1.f / (p0 + p1);
      sm_eid[lt * 2 + 0] = i0; sm_wt[lt * 2 + 0] = p0 * rn;
      sm_eid[lt * 2 + 1] = i1; sm_wt[lt * 2 + 1] = p1 * rn;
    }
  }
  __syncthreads();

  if (tid < RTOK * 2) atomicAdd(&lcnt[sm_eid[tid]], 1);
  __syncthreads();
  if (tid < E_EXP) lbase[tid] = atomicAdd(&counts[tid * CNT_STRIDE], lcnt[tid]);
  __syncthreads();
  if (tid < RTOK * 2) {
    const int e = sm_eid[tid];
    const int p = lbase[e] + atomicAdd(&lpos[e], 1);
    const int dst = e * T_TOK + p;
    tok[dst] = (t0 + (tid >> 1)) * 2 + (tid & 1);   // token*2 + k
    wts[dst] = sm_wt[tid];
  }
}

// ------------------- Grouped GEMM -- m97/m103 structure ---------------------
// 128x128 tile, BK=64, 256 threads (2x2 waves), SINGLE-buffered 32 KiB LDS,
// plain 2-barrier loop, ~3 blocks/CU (cross-block overlap hides the barrier
// drain, m114). R16: epilogue staging swizzled (col ^= ((row>>2)&3)<<4) to
// kill the 8-way ds_write_b16 bank conflict (534K in R15); read-back applies
// the matching chunk XOR (16B-aligned). Tail tiles dispatch first.
//   bid 0..255    : tail 64x128 tile of expert bid&7.
//   bid 256..2303 : bulk 128x128 tile (slot (bid-256)>>3) of expert bid&7.
#define GLDS16(gp, lp)                                                         \
  __builtin_amdgcn_global_load_lds(                                            \
      (const __attribute__((address_space(1))) void*)(gp),                     \
      (__attribute__((address_space(3))) void*)(lp), 16, 0, 0)

__global__ __launch_bounds__(256, 3) void moe_gemm(
    const ushort_t* __restrict__ x_bf, const ushort_t* __restrict__ wT,
    const float* __restrict__ bias, int* __restrict__ counts,
    const int* __restrict__ tok, const float* __restrict__ wts,
    ushort_t* __restrict__ y)
{
  __shared__ __align__(16) ushort_t As[2 * 4096];   // 16 KiB
  __shared__ __align__(16) ushort_t Bs[2 * 4096];   // 16 KiB
  __shared__ int stok[BM];
  __shared__ float swt[BM];
  __shared__ int s_spill;

  const int tid = threadIdx.x;
  const int bid = blockIdx.x;

  int ne[E_EXP], fl[E_EXP];
#pragma unroll
  for (int i = 0; i < E_EXP; i++) {
    ne[i] = counts[i * CNT_STRIDE];
    fl[i] = ne[i] >> 7;                 // floor(n_e / 128)
  }

  const int l = tid & 63;
  const int wid = tid >> 6;             // 0..3
  const int fr = l & 15;
  const int g = l >> 4;

  if (bid >= 256) {
    // ================= BULK: 128x128 single-buffer 2-barrier ================
    int e = bid & 7;                    // = XCD (round-robin; 256%8==0)
    int q = (bid - 256) >> 3;           // 0..255 home slot
    const int home = fl[e] * 8;
    if (q >= (home < 256 ? home : 256)) {
      // overflow tiles (n_e > 4096): claim via atomic among unused bids
      int sc[E_EXP], spill_total = 0;
#pragma unroll
      for (int i = 0; i < E_EXP; i++) {
        sc[i] = fl[i] * 8 > 256 ? fl[i] * 8 - 256 : 0;
        spill_total += sc[i];
      }
      if (spill_total == 0) return;
      if (tid == 0) s_spill = atomicAdd(&counts[520], 1);
      __syncthreads();
      int k = s_spill;
      if (k >= spill_total) return;
      int done = 0;
#pragma unroll
      for (int i = 0; i < E_EXP; i++) {
        if (!done) { if (k < sc[i]) { e = i; done = 1; } else k -= sc[i]; }
      }
      q = 256 + k;
    }
    const int mt = q >> 3;              // < fl[e] -> all 128 rows valid
    const int nt = q & 7;               // 0..7

    if (tid < BM) {
      stok[tid] = tok[e * T_TOK + mt * BM + tid];   // token*2+k
      swt[tid] = wts[e * T_TOK + mt * BM + tid];
    }
    __syncthreads();

    // Staging: K-half = 128 rows x 4 chunks(16B) = 512 = 256 thr x 2.
    // Phys chunk p = tid + i*256 -> row p>>2, slot p&3; logical chunk =
    // slot ^ ((row>>1)&3) applied on the SOURCE address (LDS dest linear).
    const int r0 = tid >> 2;                         // 0..63
    const int cp = (tid & 3) ^ ((tid >> 3) & 3);
    const ushort_t* wTe = wT + (size_t)e * H_DIM * H_DIM;
    const ushort_t* aP0 = x_bf + (size_t)(stok[r0] >> 1) * H_DIM + cp * 8;
    const ushort_t* aP1 = x_bf + (size_t)(stok[r0 + 64] >> 1) * H_DIM + cp * 8;
    const ushort_t* bP0 = wTe + (size_t)(nt * BN + r0) * H_DIM + cp * 8;
    const ushort_t* bP1 = wTe + (size_t)(nt * BN + r0 + 64) * H_DIM + cp * 8;
    const int d0 = tid * 8;
    const int d1 = (tid + 256) * 8;

#define STAGE8(t)                                                              \
  do {                                                                         \
    GLDS16(aP0 + (t) * BK +  0, &As[0 * 4096 + d0]);                           \
    GLDS16(aP1 + (t) * BK +  0, &As[0 * 4096 + d1]);                           \
    GLDS16(aP0 + (t) * BK + 32, &As[1 * 4096 + d0]);                           \
    GLDS16(aP1 + (t) * BK + 32, &As[1 * 4096 + d1]);                           \
    GLDS16(bP0 + (t) * BK +  0, &Bs[0 * 4096 + d0]);                           \
    GLDS16(bP1 + (t) * BK +  0, &Bs[0 * 4096 + d1]);                           \
    GLDS16(bP0 + (t) * BK + 32, &Bs[1 * 4096 + d0]);                           \
    GLDS16(bP1 + (t) * BK + 32, &Bs[1 * 4096 + d1]);                           \
  } while (0)

    const int wm = wid >> 1, wn = wid & 1;      // 2x2 waves over 128x128
    const int sl = g ^ ((l >> 1) & 3);          // swizzled slot-in-half
    const int arow0 = wm * 64 + fr;
    const int brow0 = wn * 64 + fr;

    f32x4 acc[4][4] = {};

#pragma unroll 1
    for (int t = 0; t < NKT; ++t) {
      if (t) __syncthreads();       // prev compute done before overwrite
      STAGE8(t);
      __syncthreads();              // compiler emits vmcnt(0) drain + barrier
#pragma unroll
      for (int kk = 0; kk < 2; kk++) {
        bf16x8 af[4], bv[4];
#pragma unroll
        for (int mi = 0; mi < 4; mi++)
          af[mi] = *reinterpret_cast<const bf16x8*>(
              &As[kk * 4096 + (arow0 + mi * 16) * 32 + sl * 8]);
#pragma unroll
        for (int nj = 0; nj < 4; nj++)
          bv[nj] = *reinterpret_cast<const bf16x8*>(
              &Bs[kk * 4096 + (brow0 + nj * 16) * 32 + sl * 8]);
        __builtin_amdgcn_s_setprio(1);
#pragma unroll
        for (int mi = 0; mi < 4; mi++)
#pragma unroll
          for (int nj = 0; nj < 4; nj++)
            acc[mi][nj] = __builtin_amdgcn_mfma_f32_16x16x32_bf16(
                af[mi], bv[nj], acc[mi][nj], 0, 0, 0);
        __builtin_amdgcn_s_setprio(0);
      }
    }

    // Epilogue: C/D layout col=lane&15, row=(lane>>4)*4+reg.
    // Stage weighted+biased bf16 into LDS with col ^= ((row>>2)&3)<<4
    // (write-side bank spread; (row>>2)&3 == g varies across the wave),
    // then 8 coalesced 16B stores per thread (chunk ^= ((row>>2)&3)<<1).
    __syncthreads();   // all LDS reads of the K-loop done
    float bias4[4];
#pragma unroll
    for (int nj = 0; nj < 4; nj++)
      bias4[nj] = bias[e * H_DIM + nt * BN + wn * 64 + nj * 16 + fr];
#pragma unroll
    for (int mi = 0; mi < 4; mi++) {
      const int rr0 = wm * 64 + mi * 16 + g * 4;
#pragma unroll
      for (int r = 0; r < 4; r++) {
        const int row = rr0 + r;
        const float wgt = swt[row];
        const int sw = ((row >> 2) & 3) << 4;
#pragma unroll
        for (int nj = 0; nj < 4; nj++) {
          const int col = (wn * 64 + nj * 16 + fr) ^ sw;
          const ushort_t v = f2bf(wgt * (acc[mi][nj][r] + bias4[nj]));
          if (row < 64) As[row * 128 + col] = v;
          else          Bs[(row - 64) * 128 + col] = v;
        }
      }
    }
    __syncthreads();
#pragma unroll
    for (int i = 0; i < 8; i++) {
      const int c = tid + i * 256;       // 0..2047
      const int row = c >> 4;            // 0..127
      const int ci = (c & 15) ^ (((row >> 2) & 3) << 1);
      const ushort_t* src = (row < 64) ? &As[row * 128 + ci * 8]
                                       : &Bs[(row - 64) * 128 + ci * 8];
      ushort_t* dst = y + (size_t)stok[row] * H_DIM + nt * BN + (c & 15) * 8;
      *reinterpret_cast<int4*>(dst) = *reinterpret_cast<const int4*>(src);
    }
  } else {
    // ============ TAIL: 64x128 single-buffer 2-barrier ======================
    const int e = bid & 7;              // = XCD, best-effort pinning
    const int tq = bid >> 3;            // 0..31
    const int rem = ne[e] - (fl[e] << 7);
    const int tcnt = (rem + 63) >> 6;   // 64-row tail tiles, 0..2
    if (tq >= tcnt * 8) return;
    const int mtt = tq >> 3;            // 0..1
    const int ntt = tq & 7;             // 0..7 (128-wide N-tiles)
    const int row0 = (fl[e] << 7) + mtt * 64;
    int valid = ne[e] - row0; if (valid > 64) valid = 64;

    if (tid < 64) {
      int slot = row0 + tid;
      if (slot >= ne[e]) slot = ne[e] - 1;   // clamp; masked on store
      stok[tid] = tok[e * T_TOK + slot];
      swt[tid] = wts[e * T_TOK + slot];
    }
    __syncthreads();

    // A 64x64 = 512 chunks (2/thr), B 128x64 = 1024 chunks (4/thr).
    // Logical chunk = (tid&7) ^ (row&7) (full 3-bit row-XOR, verified).
    const ushort_t* wTe = wT + (size_t)e * H_DIM * H_DIM;
    const int trow = tid >> 3;                       // 0..31
    const int tlc = (tid & 7) ^ (trow & 7);
    const ushort_t* taS0 = x_bf + (size_t)(stok[trow] >> 1) * H_DIM + tlc * 8;
    const ushort_t* taS1 = x_bf + (size_t)(stok[trow + 32] >> 1) * H_DIM + tlc * 8;
    const ushort_t* tbS0 = wTe + (size_t)(ntt * 128 + trow) * H_DIM + tlc * 8;
    const ushort_t* tbS1 = tbS0 + (size_t)32 * H_DIM;
    const ushort_t* tbS2 = tbS0 + (size_t)64 * H_DIM;
    const ushort_t* tbS3 = tbS0 + (size_t)96 * H_DIM;

#define TSTAGE1(t)                                                             \
  do {                                                                         \
    GLDS16(taS0 + (t) * BK, &As[tid * 8]);                                     \
    GLDS16(taS1 + (t) * BK, &As[(tid + 256) * 8]);                             \
    GLDS16(tbS0 + (t) * BK, &Bs[tid * 8]);                                     \
    GLDS16(tbS1 + (t) * BK, &Bs[(tid + 256) * 8]);                             \
    GLDS16(tbS2 + (t) * BK, &Bs[(tid + 512) * 8]);                             \
    GLDS16(tbS3 + (t) * BK, &Bs[(tid + 768) * 8]);                             \
  } while (0)

    const int tph0 = (g ^ (fr & 7)) * 8;             // phys chunk, kk=0
    const int tph1 = ((4 ^ g) ^ (fr & 7)) * 8;       // kk=1

    f32x4 tacc[2][4] = {};

#pragma unroll 1
    for (int t = 0; t < NKT; ++t) {
      if (t) __syncthreads();
      TSTAGE1(t);
      __syncthreads();
#pragma unroll
      for (int kk = 0; kk < 2; kk++) {
        const int ph = kk ? tph1 : tph0;
#pragma unroll
        for (int nf = 0; nf < 2; nf++) {
          const bf16x8 tbv = *reinterpret_cast<const bf16x8*>(
              &Bs[(wid * 32 + nf * 16 + fr) * 64 + ph]);
#pragma unroll
          for (int mi = 0; mi < 4; mi++) {
            const bf16x8 tav = *reinterpret_cast<const bf16x8*>(
                &As[(mi * 16 + fr) * 64 + ph]);
            tacc[nf][mi] = __builtin_amdgcn_mfma_f32_16x16x32_bf16(
                tav, tbv, tacc[nf][mi], 0, 0, 0);
          }
        }
      }
    }

    // Epilogue: stage into As as [64][128] bf16 (same write swizzle), then
    // coalesced stores.
    __syncthreads();
    float bs2[2];
#pragma unroll
    for (int nf = 0; nf < 2; nf++)
      bs2[nf] = bias[e * H_DIM + ntt * 128 + wid * 32 + nf * 16 + fr];
#pragma unroll
    for (int nf = 0; nf < 2; nf++) {
#pragma unroll
      for (int mi = 0; mi < 4; mi++) {
        const int rb = mi * 16 + g * 4;
#pragma unroll
        for (int r = 0; r < 4; r++) {
          const int row = rb + r;
          const int col = (wid * 32 + nf * 16 + fr) ^ (((row >> 2) & 3) << 4);
          As[row * 128 + col] = f2bf(swt[row] * (tacc[nf][mi][r] + bs2[nf]));
        }
      }
    }
    __syncthreads();
#pragma unroll
    for (int i = 0; i < 4; i++) {
      const int c = tid + i * 256;       // 0..1023
      const int row = c >> 4;            // 0..63
      const int ci = (c & 15) ^ (((row >> 2) & 3) << 1);
      if (row < valid) {
        ushort_t* dst = y + (size_t)stok[row] * H_DIM + ntt * 128 + (c & 15) * 8;
        *reinterpret_cast<int4*>(dst) =
            *reinterpret_cast<const int4*>(&As[row * 128 + ci * 8]);
      }
    }
  }
}

// ------------- combine: out[t] = y[t*2] + y[t*2+1] (token-major) ------------
// 2048 blocks x 4 tokens each: larger contiguous read/write per block.
__global__ __launch_bounds__(256) void combine_kernel(
    const ushort_t* __restrict__ y, float* __restrict__ out)
{
#pragma unroll
  for (int j = 0; j < 4; j++) {
    const int t = blockIdx.x * 4 + j;
    const ushort_t* r0 = y + (size_t)(t * 2) * H_DIM;
    const ushort_t* r1 = r0 + H_DIM;
    float* o = out + (size_t)t * H_DIM;
    const int h = threadIdx.x * 4;
    const ushort4 u0 = *reinterpret_cast<const ushort4*>(r0 + h);
    const ushort4 u1 = *reinterpret_cast<const ushort4*>(r1 + h);
    float4 v;
    union { uint32_t u; float f; } c;
    c.u = (uint32_t)u0.x << 16; v.x = c.f; c.u = (uint32_t)u1.x << 16; v.x += c.f;
    c.u = (uint32_t)u0.y << 16; v.y = c.f; c.u = (uint32_t)u1.y << 16; v.y += c.f;
    c.u = (uint32_t)u0.z << 16; v.z = c.f; c.u = (uint32_t)u1.z << 16; v.z += c.f;
    c.u = (uint32_t)u0.w << 16; v.w = c.f; c.u = (uint32_t)u1.w << 16; v.w += c.f;
    *reinterpret_cast<float4*>(o + h) = v;
  }
}

extern "C" void kernel_launch(void* const* d_in, const int* in_sizes, int n_in,
                              void* d_out, int out_size, void* d_ws, size_t ws_size,
                              hipStream_t stream)
{
  const float* x  = (const float*)d_in[0];
  const float* gw = (const float*)d_in[1];
  const float* gb = (const float*)d_in[2];
  const float* ew = (const float*)d_in[3];
  const float* eb = (const float*)d_in[4];

  float* out = (float*)d_out;
  float* out_final = out;                                  // [T,H] f32
  float* out_idx   = out + (size_t)T_TOK * H_DIM;          // [T,2] as f32
  float* out_probs = out_idx + (size_t)T_TOK * 2;          // [T,E] f32

  char* ws = (char*)d_ws;
  size_t off = 0;
  int*      counts  = (int*)(ws + off); off += 4096;
  int*      tok     = (int*)(ws + off); off += (size_t)E_EXP * T_TOK * 4;
  float*    wts     = (float*)(ws + off); off += (size_t)E_EXP * T_TOK * 4;
  ushort_t* x_bf    = (ushort_t*)(ws + off); off += (size_t)T_TOK * H_DIM * 2;
  ushort_t* wT      = (ushort_t*)(ws + off); off += (size_t)E_EXP * H_DIM * H_DIM * 2;
  ushort_t* y       = (ushort_t*)(ws + off); off += (size_t)T_TOK * 2 * H_DIM * 2;
  // total ~82 MB of d_ws

  hipMemsetAsync(counts, 0, 4096, stream);   // zeroes counts + spill queue

  router_transpose<<<RBLOCKS + TP_BLOCKS, 256, 0, stream>>>(
      x, gw, gb, ew, out_idx, out_probs, counts, tok, wts, x_bf, wT);
  moe_gemm<<<NWG_G, 256, 0, stream>>>(x_bf, wT, eb, counts, tok, wts, y);
  combine_kernel<<<T_TOK / 4, 256, 0, stream>>>(y, out_final);
}